// Round 5
// baseline (497.571 us; speedup 1.0000x reference)
//
#include <hip/hip_runtime.h>
#include <hip/hip_bf16.h>

#define GROUPS 16
#define BSZ    8192
#define CHN    256

using f32x4  = __attribute__((ext_vector_type(4))) float;
using bf16x8 = __attribute__((ext_vector_type(8))) __bf16;

static __device__ __forceinline__ unsigned short f32_bf16(float f) {
    unsigned int u = __builtin_bit_cast(unsigned int, f);
    u = (u + 0x7FFFu + ((u >> 16) & 1u)) >> 16;   // RNE (NaN not a concern here)
    return (unsigned short)u;
}
static __device__ __forceinline__ unsigned int pack_bf16x2(float lo, float hi) {
    return (unsigned int)f32_bf16(lo) | ((unsigned int)f32_bf16(hi) << 16);
}

// async global -> LDS, 16 B per lane. Dest is wave-uniform base + lane*16.
static __device__ __forceinline__ void gload_lds16(const void* g, void* l) {
    __builtin_amdgcn_global_load_lds(
        (const __attribute__((address_space(1))) unsigned int*)g,
        (__attribute__((address_space(3))) unsigned int*)l, 16, 0, 0);
}

// all-lanes sum within each 16-lane row via DPP row_ror (VALU pipe, no DS).
static __device__ __forceinline__ float rowsum16(float x) {
    x += __builtin_bit_cast(float, __builtin_amdgcn_mov_dpp(
             __builtin_bit_cast(int, x), 0x128, 0xf, 0xf, true)); // ror:8
    x += __builtin_bit_cast(float, __builtin_amdgcn_mov_dpp(
             __builtin_bit_cast(int, x), 0x124, 0xf, 0xf, true)); // ror:4
    x += __builtin_bit_cast(float, __builtin_amdgcn_mov_dpp(
             __builtin_bit_cast(int, x), 0x122, 0xf, 0xf, true)); // ror:2
    x += __builtin_bit_cast(float, __builtin_amdgcn_mov_dpp(
             __builtin_bit_cast(int, x), 0x121, 0xf, 0xf, true)); // ror:1
    return x;
}

// ---------------------------------------------------------------------------
// Kernel A (prep): per (group, window of 8 reflectors):
//   - write transposed weight wT[g][i][n]
//   - R[j][e] = w_e.w_j (e<j),  R[j][j] = 2/(w_j.w_j),  else 0
// (compact-WY recurrence verified on-harness in round 4 with window 16;
//  window 8 is the identical algebra regrouped.)
// Grid: 16 groups x 32 windows, 256 thr.
// ---------------------------------------------------------------------------
__global__ __launch_bounds__(256) void prep_rw(const float* __restrict__ weight,
                                               float* __restrict__ Rt,
                                               float* __restrict__ wT) {
    __shared__ float wbuf[8 * 260];
    const int t   = threadIdx.x;
    const int g   = blockIdx.x >> 5;
    const int win = blockIdx.x & 31;
    const int i0  = win * 8;
    const float* wg = weight + (size_t)g * CHN * CHN;

    // stage the 8 columns i0..i0+7, transposed: wbuf[e][n]
    {
        const int e  = t & 7;
        const int nb = t >> 3;   // 0..31
#pragma unroll
        for (int p = 0; p < 8; ++p) {
            const int n = nb + 32 * p;
            wbuf[e * 260 + n] = wg[(size_t)n * CHN + i0 + e];
        }
    }
    __syncthreads();

    // transposed copy out: wT[g][i0+e][0..255]
    {
        float* wTg = wT + (size_t)g * CHN * CHN;
        const int er = t >> 5;          // 0..7
        const int n0 = (t & 31) * 8;
        *(float4*)&wTg[(size_t)(i0 + er) * CHN + n0]     = *(const float4*)&wbuf[er * 260 + n0];
        *(float4*)&wTg[(size_t)(i0 + er) * CHN + n0 + 4] = *(const float4*)&wbuf[er * 260 + n0 + 4];
    }
    // Gram 8x8 (threads 0..63)
    if (t < 64) {
        const int e = t >> 3, f = t & 7;
        float4 pv = {0.f, 0.f, 0.f, 0.f};
#pragma unroll
        for (int n4 = 0; n4 < 64; ++n4) {
            const float4 a = *(const float4*)&wbuf[e * 260 + 4 * n4];
            const float4 b = *(const float4*)&wbuf[f * 260 + 4 * n4];
            pv.x += a.x * b.x; pv.y += a.y * b.y;
            pv.z += a.z * b.z; pv.w += a.w * b.w;
        }
        const float s = (pv.x + pv.y) + (pv.z + pv.w);
        float* Rg = Rt + ((size_t)g * 32 + win) * 64;
        Rg[f * 8 + e] = (e < f) ? s : ((e == f) ? 2.0f / s : 0.0f);
    }
}

// ---------------------------------------------------------------------------
// Kernel B (compose): M rows via blocked-WY, 8 reflectors per window.
// Window w-slice register-cached as PINNED scalars (asm "+v" in-out makes
// rematerialization illegal — round 4's compiler reloaded from global at
// VGPR_Count=60 and latency-serialized). Dots via DPP rotate-reduce;
// substitution from LDS-staged R; batched rank-8 update from pinned regs.
// ---------------------------------------------------------------------------
__global__ __launch_bounds__(256, 1) void compose_m(const float* __restrict__ wT,
                                                    const float* __restrict__ Rt,
                                                    unsigned short* __restrict__ Mt) {
    __shared__ float r8[32][8][8];   // [win][j][e] — 8 KB

    const int t    = threadIdx.x;
    const int g    = blockIdx.x >> 4;
    const int r0   = (blockIdx.x & 15) * 16;
    const int lane = t & 15;
    const int rg   = (t >> 4) & 3;
    const int wave = t >> 6;
    const int r    = r0 + wave * 4 + rg;   // this task's M row (0..255)

    // stage all R windows once (coalesced); single barrier in whole kernel
    {
        const float* Rg = Rt + (size_t)g * 2048;
        float* rl = &r8[0][0][0];
#pragma unroll
        for (int k = 0; k < 8; ++k)
            rl[t + 256 * k] = Rg[t + 256 * k];
    }
    __syncthreads();

    // m held in registers: c = 4*lane + 64*j + comp
    float4 m4[4];
#pragma unroll
    for (int j = 0; j < 4; ++j) {
        const int cb = 4 * lane + 64 * j;
        m4[j].x = (cb + 0 == r) ? 1.0f : 0.0f;
        m4[j].y = (cb + 1 == r) ? 1.0f : 0.0f;
        m4[j].z = (cb + 2 == r) ? 1.0f : 0.0f;
        m4[j].w = (cb + 3 == r) ? 1.0f : 0.0f;
    }

    const float* wTg = wT + (size_t)g * CHN * CHN;

#pragma unroll 1
    for (int iw = 0; iw < 32; ++iw) {
        const int i0 = iw * 8;
        // register-cache this lane's 16-elem slice of the 8 window vectors,
        // pinned so the compiler cannot re-load them for the update pass
        float wcx[8][4], wcy[8][4], wcz[8][4], wcw[8][4];
#pragma unroll
        for (int e = 0; e < 8; ++e) {
            const float* p = wTg + (size_t)(i0 + e) * CHN + 4 * lane;
#pragma unroll
            for (int j = 0; j < 4; ++j) {
                const float4 v = *(const float4*)(p + 64 * j);
                wcx[e][j] = v.x; wcy[e][j] = v.y;
                wcz[e][j] = v.z; wcw[e][j] = v.w;
                asm volatile("" : "+v"(wcx[e][j]), "+v"(wcy[e][j]),
                                  "+v"(wcz[e][j]), "+v"(wcw[e][j]));
            }
        }
        // 8 independent dots + DPP reduce -> every lane holds all s_e
        float s[8];
#pragma unroll
        for (int e = 0; e < 8; ++e) {
            float4 pv;
            pv.x = m4[0].x * wcx[e][0]; pv.y = m4[0].y * wcy[e][0];
            pv.z = m4[0].z * wcz[e][0]; pv.w = m4[0].w * wcw[e][0];
#pragma unroll
            for (int j = 1; j < 4; ++j) {
                pv.x += m4[j].x * wcx[e][j]; pv.y += m4[j].y * wcy[e][j];
                pv.z += m4[j].z * wcz[e][j]; pv.w += m4[j].w * wcw[e][j];
            }
            s[e] = rowsum16((pv.x + pv.y) + (pv.z + pv.w));
        }
        // forward substitution: u_j = beta_j * (s_j - sum_{e<j} u_e G[e][j])
        float u[8];
#pragma unroll
        for (int j = 0; j < 8; ++j) {
            float acc = s[j];
#pragma unroll
            for (int e = 0; e < 8; ++e)
                if (e < j) acc -= u[e] * r8[iw][j][e];
            u[j] = acc * r8[iw][j][j];
        }
        // batched rank-8 update from pinned regs
#pragma unroll
        for (int e = 0; e < 8; ++e) {
#pragma unroll
            for (int j = 0; j < 4; ++j) {
                m4[j].x -= u[e] * wcx[e][j];
                m4[j].y -= u[e] * wcy[e][j];
                m4[j].z -= u[e] * wcz[e][j];
                m4[j].w -= u[e] * wcw[e][j];
            }
        }
    }

    // write Mt[g][c][r] (bf16)
    unsigned short* mg = Mt + (size_t)g * CHN * CHN;
#pragma unroll
    for (int j = 0; j < 4; ++j) {
        const int cb = 4 * lane + 64 * j;
        mg[(size_t)(cb + 0) * CHN + r] = f32_bf16(m4[j].x);
        mg[(size_t)(cb + 1) * CHN + r] = f32_bf16(m4[j].y);
        mg[(size_t)(cb + 2) * CHN + r] = f32_bf16(m4[j].z);
        mg[(size_t)(cb + 3) * CHN + r] = f32_bf16(m4[j].w);
    }
}

// ---------------------------------------------------------------------------
// Kernel C: out[g] = x[g] (8192x256 f32->bf16) @ M[g] (256x256 bf16), f32 acc.
// Round-3 pipeline (dbuf, 1 barrier/chunk, 1-ahead prefetch) + B bank-conflict
// fix via pre-swizzled global source (gload_lds dest linear). Unchanged.
// ---------------------------------------------------------------------------
#define ABUF 2560          // A buffer: 128 rows * 20 dwords
#define BUFSZ 6656         // A (2560) + B (256*16 = 4096) dwords per buffer

__global__ __launch_bounds__(512, 4) void gemm_xm(const float* __restrict__ x,
                                                  const unsigned short* __restrict__ Mt,
                                                  float* __restrict__ out) {
    __shared__ __align__(16) unsigned int lds[2 * BUFSZ];   // 53248 B

    const int t    = threadIdx.x;
    const int g    = blockIdx.x >> 6;
    const int rb   = blockIdx.x & 63;
    const int r0   = rb * 128;
    const int l    = t & 63;
    const int wave = t >> 6;     // 0..7
    const int wr   = wave >> 2;  // 0..1
    const int wc   = wave & 3;   // 0..3
    const int lm   = l & 15;
    const int q    = l >> 4;     // 0..3

    const float*          xg = x  + ((size_t)g * BSZ + r0) * CHN;
    const unsigned short* mg = Mt +  (size_t)g * CHN * CHN;

    // staging maps
    const int ar = t >> 3;           // A row (0..63), +64 for second load
    const int as = t & 7;            // A seg: float4 index within 32-k chunk
    const int bc = (wave << 4) + ((l >> 2) & 15);   // B col for lane
    const int bq = (l & 3) ^ ((l >> 3) & 3);        // swizzled source quad
    const int rq = 4 * (q ^ ((lm >> 1) & 3));       // swizzled read quad (dw)

    f32x4 acc[4][4];
#pragma unroll
    for (int mi = 0; mi < 4; ++mi)
#pragma unroll
        for (int ni = 0; ni < 4; ++ni)
            acc[mi][ni] = (f32x4){0.f, 0.f, 0.f, 0.f};

    float4 sA[2][2];   // [set][half] — static-indexed via full unroll

    // ---- prologue: chunk 0 ----
    sA[0][0] = *(const float4*)&xg[(size_t)ar * CHN + 4 * as];
    sA[0][1] = *(const float4*)&xg[(size_t)(ar + 64) * CHN + 4 * as];
    {
        unsigned int* bb = lds + ABUF;
        gload_lds16(mg + (size_t)bc * CHN + 8 * bq,          &bb[wave * 256]);
        gload_lds16(mg + (size_t)(bc + 128) * CHN + 8 * bq,  &bb[(wave + 8) * 256]);
    }

#pragma unroll
    for (int kc = 0; kc < 8; ++kc) {
        const int cur = kc & 1;
        unsigned int* ab = lds + cur * BUFSZ;
        unsigned int* bb = ab + ABUF;

        // pack + write A chunk kc
        {
            uint2 p0, p1;
            p0.x = pack_bf16x2(sA[cur][0].x, sA[cur][0].y);
            p0.y = pack_bf16x2(sA[cur][0].z, sA[cur][0].w);
            p1.x = pack_bf16x2(sA[cur][1].x, sA[cur][1].y);
            p1.y = pack_bf16x2(sA[cur][1].z, sA[cur][1].w);
            *(uint2*)&ab[ar * 20 + 2 * as]        = p0;
            *(uint2*)&ab[(ar + 64) * 20 + 2 * as] = p1;
        }
        __syncthreads();   // buf[cur] ready; all waves finished compute kc-1

        // prefetch chunk kc+1 into the other buffer / reg set
        if (kc < 7) {
            const int nxt = cur ^ 1;
            const int k0  = (kc + 1) * 32;
            sA[nxt][0] = *(const float4*)&xg[(size_t)ar * CHN + k0 + 4 * as];
            sA[nxt][1] = *(const float4*)&xg[(size_t)(ar + 64) * CHN + k0 + 4 * as];
            unsigned int* bbn = lds + nxt * BUFSZ + ABUF;
            gload_lds16(mg + (size_t)bc * CHN + k0 + 8 * bq,         &bbn[wave * 256]);
            gload_lds16(mg + (size_t)(bc + 128) * CHN + k0 + 8 * bq, &bbn[(wave + 8) * 256]);
        }

        // compute chunk kc
        bf16x8 a[4];
#pragma unroll
        for (int mi = 0; mi < 4; ++mi) {
            const int rr = wr * 64 + mi * 16 + lm;
            a[mi] = __builtin_bit_cast(bf16x8, *(const uint4*)&ab[rr * 20 + 4 * q]);
        }
#pragma unroll
        for (int ni = 0; ni < 4; ++ni) {
            const int cc = wc * 64 + ni * 16 + lm;
            const bf16x8 b = __builtin_bit_cast(bf16x8, *(const uint4*)&bb[cc * 16 + rq]);
#pragma unroll
            for (int mi = 0; mi < 4; ++mi)
                acc[mi][ni] = __builtin_amdgcn_mfma_f32_16x16x32_bf16(
                    a[mi], b, acc[mi][ni], 0, 0, 0);
        }
    }

    // epilogue: D layout col = lane&15, row = (lane>>4)*4 + reg
    float* og = out + ((size_t)g * BSZ + r0) * CHN;
#pragma unroll
    for (int mi = 0; mi < 4; ++mi) {
#pragma unroll
        for (int ni = 0; ni < 4; ++ni) {
            const int col = wc * 64 + ni * 16 + lm;
#pragma unroll
            for (int reg = 0; reg < 4; ++reg) {
                const int row = wr * 64 + mi * 16 + q * 4 + reg;
                og[(size_t)row * CHN + col] = acc[mi][ni][reg];
            }
        }
    }
}

extern "C" void kernel_launch(void* const* d_in, const int* in_sizes, int n_in,
                              void* d_out, int out_size, void* d_ws, size_t ws_size,
                              hipStream_t stream) {
    const float* x = (const float*)d_in[0];
    const float* w = (const float*)d_in[1];
    float* out = (float*)d_out;
    unsigned short* Mt = (unsigned short*)d_ws;                       // 2 MB
    float* Rt = (float*)((char*)d_ws + (2u << 20));                   // 128 KB used
    float* wT = (float*)((char*)d_ws + (2u << 20) + (256u << 10));    // 4 MB

    hipLaunchKernelGGL(prep_rw,   dim3(GROUPS * 32), dim3(256), 0, stream, w, Rt, wT);
    hipLaunchKernelGGL(compose_m, dim3(GROUPS * 16), dim3(256), 0, stream, wT, Rt, Mt);
    hipLaunchKernelGGL(gemm_xm,   dim3(GROUPS * 64), dim3(512), 0, stream, x, Mt, out);
}

// Round 9
// 289.378 us; speedup vs baseline: 1.7194x; 1.7194x over previous
//
#include <hip/hip_runtime.h>
#include <hip/hip_bf16.h>

#define GROUPS 16
#define BSZ    8192
#define CHN    256

using f32x4  = __attribute__((ext_vector_type(4))) float;
using bf16x8 = __attribute__((ext_vector_type(8))) __bf16;

static __device__ __forceinline__ unsigned short f32_bf16(float f) {
    unsigned int u = __builtin_bit_cast(unsigned int, f);
    u = (u + 0x7FFFu + ((u >> 16) & 1u)) >> 16;   // RNE (NaN not a concern here)
    return (unsigned short)u;
}
static __device__ __forceinline__ unsigned int pack_bf16x2(float lo, float hi) {
    return (unsigned int)f32_bf16(lo) | ((unsigned int)f32_bf16(hi) << 16);
}

// async global -> LDS, 16 B per lane. Dest is wave-uniform base + lane*16.
static __device__ __forceinline__ void gload_lds16(const void* g, void* l) {
    __builtin_amdgcn_global_load_lds(
        (const __attribute__((address_space(1))) unsigned int*)g,
        (__attribute__((address_space(3))) unsigned int*)l, 16, 0, 0);
}

// all-lanes sum within each 16-lane row via DPP row_ror (VALU pipe, no DS).
static __device__ __forceinline__ float rowsum16(float x) {
    x += __builtin_bit_cast(float, __builtin_amdgcn_mov_dpp(
             __builtin_bit_cast(int, x), 0x128, 0xf, 0xf, true)); // ror:8
    x += __builtin_bit_cast(float, __builtin_amdgcn_mov_dpp(
             __builtin_bit_cast(int, x), 0x124, 0xf, 0xf, true)); // ror:4
    x += __builtin_bit_cast(float, __builtin_amdgcn_mov_dpp(
             __builtin_bit_cast(int, x), 0x122, 0xf, 0xf, true)); // ror:2
    x += __builtin_bit_cast(float, __builtin_amdgcn_mov_dpp(
             __builtin_bit_cast(int, x), 0x121, 0xf, 0xf, true)); // ror:1
    return x;
}

// ---------------------------------------------------------------------------
// Kernel A (prep): per (group, window of 8 reflectors):
//   - write transposed weight wT[g][i][n]
//   - R[j][e] = w_e.w_j (e<j),  R[j][j] = 2/(w_j.w_j),  else 0
// (compact-WY recurrence harness-verified in rounds 4 and 5.)
// Grid: 16 groups x 32 windows, 256 thr.
// ---------------------------------------------------------------------------
__global__ __launch_bounds__(256) void prep_rw(const float* __restrict__ weight,
                                               float* __restrict__ Rt,
                                               float* __restrict__ wT) {
    __shared__ float wbuf[8 * 260];
    const int t   = threadIdx.x;
    const int g   = blockIdx.x >> 5;
    const int win = blockIdx.x & 31;
    const int i0  = win * 8;
    const float* wg = weight + (size_t)g * CHN * CHN;

    // stage the 8 columns i0..i0+7, transposed: wbuf[e][n]
    {
        const int e  = t & 7;
        const int nb = t >> 3;   // 0..31
#pragma unroll
        for (int p = 0; p < 8; ++p) {
            const int n = nb + 32 * p;
            wbuf[e * 260 + n] = wg[(size_t)n * CHN + i0 + e];
        }
    }
    __syncthreads();

    // transposed copy out: wT[g][i0+e][0..255]
    {
        float* wTg = wT + (size_t)g * CHN * CHN;
        const int er = t >> 5;          // 0..7
        const int n0 = (t & 31) * 8;
        *(float4*)&wTg[(size_t)(i0 + er) * CHN + n0]     = *(const float4*)&wbuf[er * 260 + n0];
        *(float4*)&wTg[(size_t)(i0 + er) * CHN + n0 + 4] = *(const float4*)&wbuf[er * 260 + n0 + 4];
    }
    // Gram 8x8 (threads 0..63)
    if (t < 64) {
        const int e = t >> 3, f = t & 7;
        float4 pv = {0.f, 0.f, 0.f, 0.f};
#pragma unroll
        for (int n4 = 0; n4 < 64; ++n4) {
            const float4 a = *(const float4*)&wbuf[e * 260 + 4 * n4];
            const float4 b = *(const float4*)&wbuf[f * 260 + 4 * n4];
            pv.x += a.x * b.x; pv.y += a.y * b.y;
            pv.z += a.z * b.z; pv.w += a.w * b.w;
        }
        const float s = (pv.x + pv.y) + (pv.z + pv.w);
        float* Rg = Rt + ((size_t)g * 32 + win) * 64;
        Rg[f * 8 + e] = (e < f) ? s : ((e == f) ? 2.0f / s : 0.0f);
    }
}

// ---------------------------------------------------------------------------
// Kernel B (compose): blocked-WY, 8 reflectors/window, 32-lane rows.
// Each lane owns 8 columns -> window cache is only 64 floats (8e x 2 float4);
// ~110 VGPR total, well under the 256 cap at 2 waves/SIMD. Pins are TWO
// grouped asm statements AFTER all 16 loads (round 5's per-element pins
// serialized 32 load latencies per window). 512 blocks = 2 blocks/CU for
// latency overlap. Dot reduce: DPP rowsum16 + one shfl_xor(16).
// ---------------------------------------------------------------------------
__global__ __launch_bounds__(256, 2) void compose_m(const float* __restrict__ wT,
                                                    const float* __restrict__ Rt,
                                                    unsigned short* __restrict__ Mt) {
    __shared__ float r8[32][8][8];   // [win][j][e] — 8 KB

    const int t   = threadIdx.x;
    const int g   = blockIdx.x >> 5;
    const int r0  = (blockIdx.x & 31) * 8;
    const int L   = t & 31;          // lane within 32-lane row
    const int row = t >> 5;          // 0..7
    const int r   = r0 + row;        // this task's M row (0..255)

    // stage all R windows once (coalesced); single barrier in whole kernel
    {
        const float* Rg = Rt + (size_t)g * 2048;
        float* rl = &r8[0][0][0];
#pragma unroll
        for (int k = 0; k < 8; ++k)
            rl[t + 256 * k] = Rg[t + 256 * k];
    }
    __syncthreads();

    // m in registers: c = 4*L + 128*j + comp  (j=0..1, comp=0..3)
    f32x4 m4[2];
#pragma unroll
    for (int j = 0; j < 2; ++j) {
        const int cb = 4 * L + 128 * j;
        m4[j][0] = (cb + 0 == r) ? 1.0f : 0.0f;
        m4[j][1] = (cb + 1 == r) ? 1.0f : 0.0f;
        m4[j][2] = (cb + 2 == r) ? 1.0f : 0.0f;
        m4[j][3] = (cb + 3 == r) ? 1.0f : 0.0f;
    }

    const float* wTg = wT + (size_t)g * CHN * CHN;

#pragma unroll 1
    for (int iw = 0; iw < 32; ++iw) {
        const int i0 = iw * 8;
        // cache this lane's 8-elem slice of the 8 window vectors
        f32x4 wc[8][2];
#pragma unroll
        for (int e = 0; e < 8; ++e) {
            const float* p = wTg + (size_t)(i0 + e) * CHN + 4 * L;
            wc[e][0] = *(const f32x4*)(p);
            wc[e][1] = *(const f32x4*)(p + 128);
        }
        // pin AFTER all loads issued: rematerialization illegal, single
        // latency exposure (round 5's per-element pins = 32 exposures)
        asm volatile("" : "+v"(wc[0][0]), "+v"(wc[0][1]), "+v"(wc[1][0]), "+v"(wc[1][1]),
                          "+v"(wc[2][0]), "+v"(wc[2][1]), "+v"(wc[3][0]), "+v"(wc[3][1]));
        asm volatile("" : "+v"(wc[4][0]), "+v"(wc[4][1]), "+v"(wc[5][0]), "+v"(wc[5][1]),
                          "+v"(wc[6][0]), "+v"(wc[6][1]), "+v"(wc[7][0]), "+v"(wc[7][1]));

        // 8 independent dots; reduce over the 32-lane row
        float s[8];
#pragma unroll
        for (int e = 0; e < 8; ++e) {
            f32x4 pv = m4[0] * wc[e][0] + m4[1] * wc[e][1];
            float d = (pv[0] + pv[1]) + (pv[2] + pv[3]);
            d = rowsum16(d);
            d += __shfl_xor(d, 16);
            s[e] = d;
        }
        // forward substitution: u_j = beta_j * (s_j - sum_{e<j} u_e G[e][j])
        float u[8];
#pragma unroll
        for (int j = 0; j < 8; ++j) {
            float acc = s[j];
#pragma unroll
            for (int e = 0; e < 8; ++e)
                if (e < j) acc -= u[e] * r8[iw][j][e];
            u[j] = acc * r8[iw][j][j];
        }
        // batched rank-8 update from cached regs
#pragma unroll
        for (int e = 0; e < 8; ++e) {
#pragma unroll
            for (int j = 0; j < 2; ++j)
                m4[j] = m4[j] - u[e] * wc[e][j];
        }
    }

    // write Mt[g][c][r] (bf16)
    unsigned short* mg = Mt + (size_t)g * CHN * CHN;
#pragma unroll
    for (int j = 0; j < 2; ++j) {
        const int cb = 4 * L + 128 * j;
        mg[(size_t)(cb + 0) * CHN + r] = f32_bf16(m4[j][0]);
        mg[(size_t)(cb + 1) * CHN + r] = f32_bf16(m4[j][1]);
        mg[(size_t)(cb + 2) * CHN + r] = f32_bf16(m4[j][2]);
        mg[(size_t)(cb + 3) * CHN + r] = f32_bf16(m4[j][3]);
    }
}

// ---------------------------------------------------------------------------
// Kernel C: out[g] = x[g] (8192x256 f32->bf16) @ M[g] (256x256 bf16), f32 acc.
// Round-3 pipeline (dbuf, 1 barrier/chunk, 1-ahead prefetch) + B bank-conflict
// fix via pre-swizzled global source (gload_lds dest linear). Unchanged.
// ---------------------------------------------------------------------------
#define ABUF 2560          // A buffer: 128 rows * 20 dwords
#define BUFSZ 6656         // A (2560) + B (256*16 = 4096) dwords per buffer

__global__ __launch_bounds__(512, 4) void gemm_xm(const float* __restrict__ x,
                                                  const unsigned short* __restrict__ Mt,
                                                  float* __restrict__ out) {
    __shared__ __align__(16) unsigned int lds[2 * BUFSZ];   // 53248 B

    const int t    = threadIdx.x;
    const int g    = blockIdx.x >> 6;
    const int rb   = blockIdx.x & 63;
    const int r0   = rb * 128;
    const int l    = t & 63;
    const int wave = t >> 6;     // 0..7
    const int wr   = wave >> 2;  // 0..1
    const int wc   = wave & 3;   // 0..3
    const int lm   = l & 15;
    const int q    = l >> 4;     // 0..3

    const float*          xg = x  + ((size_t)g * BSZ + r0) * CHN;
    const unsigned short* mg = Mt +  (size_t)g * CHN * CHN;

    // staging maps
    const int ar = t >> 3;           // A row (0..63), +64 for second load
    const int as = t & 7;            // A seg: float4 index within 32-k chunk
    const int bc = (wave << 4) + ((l >> 2) & 15);   // B col for lane
    const int bq = (l & 3) ^ ((l >> 3) & 3);        // swizzled source quad
    const int rq = 4 * (q ^ ((lm >> 1) & 3));       // swizzled read quad (dw)

    f32x4 acc[4][4];
#pragma unroll
    for (int mi = 0; mi < 4; ++mi)
#pragma unroll
        for (int ni = 0; ni < 4; ++ni)
            acc[mi][ni] = (f32x4){0.f, 0.f, 0.f, 0.f};

    float4 sA[2][2];   // [set][half] — static-indexed via full unroll

    // ---- prologue: chunk 0 ----
    sA[0][0] = *(const float4*)&xg[(size_t)ar * CHN + 4 * as];
    sA[0][1] = *(const float4*)&xg[(size_t)(ar + 64) * CHN + 4 * as];
    {
        unsigned int* bb = lds + ABUF;
        gload_lds16(mg + (size_t)bc * CHN + 8 * bq,          &bb[wave * 256]);
        gload_lds16(mg + (size_t)(bc + 128) * CHN + 8 * bq,  &bb[(wave + 8) * 256]);
    }

#pragma unroll
    for (int kc = 0; kc < 8; ++kc) {
        const int cur = kc & 1;
        unsigned int* ab = lds + cur * BUFSZ;
        unsigned int* bb = ab + ABUF;

        // pack + write A chunk kc
        {
            uint2 p0, p1;
            p0.x = pack_bf16x2(sA[cur][0].x, sA[cur][0].y);
            p0.y = pack_bf16x2(sA[cur][0].z, sA[cur][0].w);
            p1.x = pack_bf16x2(sA[cur][1].x, sA[cur][1].y);
            p1.y = pack_bf16x2(sA[cur][1].z, sA[cur][1].w);
            *(uint2*)&ab[ar * 20 + 2 * as]        = p0;
            *(uint2*)&ab[(ar + 64) * 20 + 2 * as] = p1;
        }
        __syncthreads();   // buf[cur] ready; all waves finished compute kc-1

        // prefetch chunk kc+1 into the other buffer / reg set
        if (kc < 7) {
            const int nxt = cur ^ 1;
            const int k0  = (kc + 1) * 32;
            sA[nxt][0] = *(const float4*)&xg[(size_t)ar * CHN + k0 + 4 * as];
            sA[nxt][1] = *(const float4*)&xg[(size_t)(ar + 64) * CHN + k0 + 4 * as];
            unsigned int* bbn = lds + nxt * BUFSZ + ABUF;
            gload_lds16(mg + (size_t)bc * CHN + k0 + 8 * bq,         &bbn[wave * 256]);
            gload_lds16(mg + (size_t)(bc + 128) * CHN + k0 + 8 * bq, &bbn[(wave + 8) * 256]);
        }

        // compute chunk kc
        bf16x8 a[4];
#pragma unroll
        for (int mi = 0; mi < 4; ++mi) {
            const int rr = wr * 64 + mi * 16 + lm;
            a[mi] = __builtin_bit_cast(bf16x8, *(const uint4*)&ab[rr * 20 + 4 * q]);
        }
#pragma unroll
        for (int ni = 0; ni < 4; ++ni) {
            const int cc = wc * 64 + ni * 16 + lm;
            const bf16x8 b = __builtin_bit_cast(bf16x8, *(const uint4*)&bb[cc * 16 + rq]);
#pragma unroll
            for (int mi = 0; mi < 4; ++mi)
                acc[mi][ni] = __builtin_amdgcn_mfma_f32_16x16x32_bf16(
                    a[mi], b, acc[mi][ni], 0, 0, 0);
        }
    }

    // epilogue: D layout col = lane&15, row = (lane>>4)*4 + reg
    float* og = out + ((size_t)g * BSZ + r0) * CHN;
#pragma unroll
    for (int mi = 0; mi < 4; ++mi) {
#pragma unroll
        for (int ni = 0; ni < 4; ++ni) {
            const int col = wc * 64 + ni * 16 + lm;
#pragma unroll
            for (int reg = 0; reg < 4; ++reg) {
                const int row = wr * 64 + mi * 16 + q * 4 + reg;
                og[(size_t)row * CHN + col] = acc[mi][ni][reg];
            }
        }
    }
}

extern "C" void kernel_launch(void* const* d_in, const int* in_sizes, int n_in,
                              void* d_out, int out_size, void* d_ws, size_t ws_size,
                              hipStream_t stream) {
    const float* x = (const float*)d_in[0];
    const float* w = (const float*)d_in[1];
    float* out = (float*)d_out;
    unsigned short* Mt = (unsigned short*)d_ws;                       // 2 MB
    float* Rt = (float*)((char*)d_ws + (2u << 20));                   // 128 KB used
    float* wT = (float*)((char*)d_ws + (2u << 20) + (256u << 10));    // 4 MB

    hipLaunchKernelGGL(prep_rw,   dim3(GROUPS * 32), dim3(256), 0, stream, w, Rt, wT);
    hipLaunchKernelGGL(compose_m, dim3(GROUPS * 32), dim3(256), 0, stream, wT, Rt, Mt);
    hipLaunchKernelGGL(gemm_xm,   dim3(GROUPS * 64), dim3(512), 0, stream, x, Mt, out);
}